// Round 1
// baseline (394.160 us; speedup 1.0000x reference)
//
#include <hip/hip_runtime.h>
#include <math.h>

#define BN   8192
#define DIMD 64
#define CLD  128
#define KTOK 8

__device__ __forceinline__ float gelu_exact(float x){
    return 0.5f * x * (1.0f + erff(x * 0.70710678118654752f));
}

__device__ __forceinline__ float wave_sum64(float v){
    #pragma unroll
    for(int off = 32; off >= 1; off >>= 1) v += __shfl_xor(v, off, 64);
    return v;
}

// K0: transpose fte_w1 [64,81] -> [81,64] and fte_w2 [64,64] -> [64,64]
// so the main kernel's weight reads are coalesced (lane = output dim).
__global__ void prep_weights(const float* __restrict__ w1, const float* __restrict__ w2,
                             float* __restrict__ w1t, float* __restrict__ w2t){
    int idx = blockIdx.x * blockDim.x + threadIdx.x;
    if(idx < 64*81){ int o = idx / 81, c = idx % 81; w1t[c*64 + o] = w1[idx]; }
    if(idx < 64*64){ int o = idx / 64, c = idx % 64; w2t[c*64 + o] = w2[idx]; }
}

// Main fused kernel: one 64-lane wave per pixel; lane t = feature dim.
__global__ __launch_bounds__(64) void decoder_main(
    const float* __restrict__ cost_maps, const float* __restrict__ cost_memory,
    const float* __restrict__ coords1,
    const float* __restrict__ w1t, const float* __restrict__ fte_b1,
    const float* __restrict__ w2t, const float* __restrict__ fte_b2,
    const float* __restrict__ ln1_g, const float* __restrict__ ln1_b,
    const float* __restrict__ ln2_g, const float* __restrict__ ln2_b,
    const float* __restrict__ wq, const float* __restrict__ bq,
    const float* __restrict__ wk, const float* __restrict__ bk,
    const float* __restrict__ wv, const float* __restrict__ bv,
    const float* __restrict__ wp, const float* __restrict__ bp,
    const float* __restrict__ fw1, const float* __restrict__ fb1,
    const float* __restrict__ fw2, const float* __restrict__ fb2,
    float* __restrict__ out_cg)
{
    __shared__ float corr_s[81];
    __shared__ float cm_s[KTOK * CLD];   // this pixel's cost_memory [8][128]
    __shared__ float vec_s[2 * DIMD];

    const int pix = blockIdx.x;
    const int t   = threadIdx.x;
    const int b = pix >> 12;
    const int h = (pix >> 6) & 63;
    const int w = pix & 63;

    const float cx = coords1[((b*2 + 0)*64 + h)*64 + w];
    const float cy = coords1[((b*2 + 1)*64 + h)*64 + w];

    // stage cost_memory (1024 floats, coalesced)
    const float* cmp = cost_memory + (size_t)pix * (KTOK * CLD);
    #pragma unroll
    for(int i = 0; i < 16; i++) cm_s[i*64 + t] = cmp[i*64 + t];

    // ---- correlation window: 81 bilinear samples from this pixel's 64x64 map
    // samp(i,j) = (x + d[i], y + d[j]), d = -4..4 ; zero padding outside.
    const float* cmap = cost_maps + (size_t)pix * 4096;
    for(int e = t; e < 81; e += 64){
        int i = e / 9, j = e % 9;
        float sx = cx + (float)(i - 4);
        float sy = cy + (float)(j - 4);
        float x0 = floorf(sx), y0 = floorf(sy);
        float wx = sx - x0,   wy = sy - y0;
        float acc = 0.f;
        #pragma unroll
        for(int dy = 0; dy < 2; dy++){
            #pragma unroll
            for(int dx = 0; dx < 2; dx++){
                float xf = x0 + (float)dx, yf = y0 + (float)dy;
                bool valid = (xf >= 0.f) && (xf <= 63.f) && (yf >= 0.f) && (yf <= 63.f);
                int xi = min(max((int)xf, 0), 63);
                int yi = min(max((int)yf, 0), 63);
                float v = valid ? cmap[yi*64 + xi] : 0.f;
                float wgt = (dx ? wx : 1.f - wx) * (dy ? wy : 1.f - wy);
                acc += v * wgt;
            }
        }
        corr_s[e] = acc;
    }
    __syncthreads();

    // ---- FTE: 81->64, GELU, 64->64
    float q1 = fte_b1[t];
    #pragma unroll 4
    for(int c = 0; c < 81; c++) q1 += corr_s[c] * w1t[c*64 + t];
    q1 = gelu_exact(q1);
    vec_s[t] = q1;
    __syncthreads();

    float shortv = fte_b2[t];
    #pragma unroll 4
    for(int c = 0; c < 64; c++) shortv += vec_s[c] * w2t[c*64 + t];

    // ---- LN1 + sine position embedding + Wq
    float mean = wave_sum64(shortv) * (1.f/64.f);
    float d0   = shortv - mean;
    float var  = wave_sum64(d0*d0) * (1.f/64.f);
    float qn   = d0 * rsqrtf(var + 1e-5f) * ln1_g[t] + ln1_b[t];

    // enc layout: [sin(a0..15), cos(a0..15), sin(b0..15), cos(b0..15)]
    int   fi    = t & 15;
    float coord = (t < 32) ? cx : cy;
    float ang   = 3.14f * coord * (float)fi / 200.0f;
    float enc   = (t & 16) ? cosf(ang) : sinf(ang);

    __syncthreads();
    vec_s[t] = qn + enc;
    __syncthreads();

    float qlin = bq[t];
    #pragma unroll 4
    for(int c = 0; c < 64; c++) qlin += vec_s[c] * wq[c*64 + t];

    // ---- K projection: k[j][t] = sum_c cm[j,c] * wk[c,t] + bk[t]
    float kk[KTOK];
    #pragma unroll
    for(int j = 0; j < KTOK; j++) kk[j] = bk[t];
    #pragma unroll 4
    for(int c = 0; c < CLD; c++){
        float wkc = wk[c*64 + t];
        #pragma unroll
        for(int j = 0; j < KTOK; j++) kk[j] += cm_s[j*CLD + c] * wkc;
    }

    // ---- scores per head (head = t/8, dim = t%8), softmax over 8 tokens
    float s_[KTOK];
    #pragma unroll
    for(int j = 0; j < KTOK; j++){
        float p = qlin * kk[j];
        p += __shfl_xor(p, 1, 64);
        p += __shfl_xor(p, 2, 64);
        p += __shfl_xor(p, 4, 64);
        s_[j] = p * 0.35355339059327373f;   // hd^-0.5, hd=8
    }
    float mx = s_[0];
    #pragma unroll
    for(int j = 1; j < KTOK; j++) mx = fmaxf(mx, s_[j]);
    float se = 0.f;
    #pragma unroll
    for(int j = 0; j < KTOK; j++){ s_[j] = expf(s_[j] - mx); se += s_[j]; }
    float inv = 1.f / se;
    #pragma unroll
    for(int j = 0; j < KTOK; j++) s_[j] *= inv;

    // ---- V projection + attention output
    float vv[KTOK];
    #pragma unroll
    for(int j = 0; j < KTOK; j++) vv[j] = bv[t];
    #pragma unroll 4
    for(int c = 0; c < CLD; c++){
        float wvc = wv[c*64 + t];
        #pragma unroll
        for(int j = 0; j < KTOK; j++) vv[j] += cm_s[j*CLD + c] * wvc;
    }
    float attno = 0.f;
    #pragma unroll
    for(int j = 0; j < KTOK; j++) attno += s_[j] * vv[j];

    // ---- wp on concat(out, short), residual
    __syncthreads();
    vec_s[t]      = attno;
    vec_s[64 + t] = shortv;
    __syncthreads();
    float x = bp[t];
    #pragma unroll 4
    for(int c = 0; c < 128; c++) x += vec_s[c] * wp[c*64 + t];
    x += shortv;

    // ---- LN2 + FFN, residual
    float m2 = wave_sum64(x) * (1.f/64.f);
    float dd = x - m2;
    float v2 = wave_sum64(dd*dd) * (1.f/64.f);
    float xn = dd * rsqrtf(v2 + 1e-5f) * ln2_g[t] + ln2_b[t];
    __syncthreads();
    vec_s[t] = xn;
    __syncthreads();
    float h1v = fb1[t];
    #pragma unroll 4
    for(int c = 0; c < 64; c++) h1v += vec_s[c] * fw1[c*64 + t];
    h1v = gelu_exact(h1v);
    __syncthreads();
    vec_s[t] = h1v;
    __syncthreads();
    float f2 = fb2[t];
    #pragma unroll 4
    for(int c = 0; c < 64; c++) f2 += vec_s[c] * fw2[c*64 + t];
    x += f2;

    // cost_global [B, DIM, H1, W1]
    out_cg[(((size_t)(b*64 + t))*64 + h)*64 + w] = x;
}

// Convex upsampling: one wave per coarse pixel, lane t = (r*8+s) subpixel.
__global__ __launch_bounds__(64) void upsample_kernel(
    const float* __restrict__ coords1, const float* __restrict__ up_mask,
    float* __restrict__ out)
{
    const int pix = blockIdx.x;
    const int t   = threadIdx.x;
    const int b = pix >> 12;
    const int h = (pix >> 6) & 63;
    const int w = pix & 63;

    float m[9];
    #pragma unroll
    for(int k = 0; k < 9; k++)
        m[k] = up_mask[(((size_t)b*576 + k*64 + t)*64 + h)*64 + w];
    float mx = m[0];
    #pragma unroll
    for(int k = 1; k < 9; k++) mx = fmaxf(mx, m[k]);
    float se = 0.f;
    #pragma unroll
    for(int k = 0; k < 9; k++){ m[k] = expf(m[k] - mx); se += m[k]; }
    float inv = 1.f / se;

    float ox = 0.f, oy = 0.f;
    #pragma unroll
    for(int k = 0; k < 9; k++){
        int i = k / 3, j = k % 3;
        int hh = h + i - 1, ww = w + j - 1;
        float fx = 0.f, fy = 0.f;
        if(hh >= 0 && hh < 64 && ww >= 0 && ww < 64){
            float cxv = coords1[((b*2 + 0)*64 + hh)*64 + ww];
            float cyv = coords1[((b*2 + 1)*64 + hh)*64 + ww];
            fx = 8.f * (cxv - (float)ww);   // flow = coords1 - coords0, scaled, zero-padded
            fy = 8.f * (cyv - (float)hh);
        }
        ox += m[k] * fx;
        oy += m[k] * fy;
    }
    ox *= inv; oy *= inv;

    const int r = t >> 3, s = t & 7;
    out[(((size_t)(b*2 + 0))*512 + (h*8 + r))*512 + (w*8 + s)] = ox;
    out[(((size_t)(b*2 + 1))*512 + (h*8 + r))*512 + (w*8 + s)] = oy;
}

extern "C" void kernel_launch(void* const* d_in, const int* in_sizes, int n_in,
                              void* d_out, int out_size, void* d_ws, size_t ws_size,
                              hipStream_t stream)
{
    const float* cost_maps   = (const float*)d_in[0];
    const float* cost_memory = (const float*)d_in[1];
    const float* coords1     = (const float*)d_in[2];
    const float* up_mask     = (const float*)d_in[3];
    const float* fte_w1      = (const float*)d_in[4];
    const float* fte_b1      = (const float*)d_in[5];
    const float* fte_w2      = (const float*)d_in[6];
    const float* fte_b2      = (const float*)d_in[7];
    const float* ln1_g       = (const float*)d_in[8];
    const float* ln1_b       = (const float*)d_in[9];
    const float* ln2_g       = (const float*)d_in[10];
    const float* ln2_b       = (const float*)d_in[11];
    const float* wq          = (const float*)d_in[12];
    const float* bq          = (const float*)d_in[13];
    const float* wk          = (const float*)d_in[14];
    const float* bk          = (const float*)d_in[15];
    const float* wv          = (const float*)d_in[16];
    const float* bv          = (const float*)d_in[17];
    const float* wp          = (const float*)d_in[18];
    const float* bp          = (const float*)d_in[19];
    const float* fw1         = (const float*)d_in[20];
    const float* fb1         = (const float*)d_in[21];
    const float* fw2         = (const float*)d_in[22];
    const float* fb2         = (const float*)d_in[23];
    float* out = (float*)d_out;

    float* w1t = (float*)d_ws;          // 81*64 floats
    float* w2t = w1t + 81*64;           // 64*64 floats

    prep_weights<<<40, 256, 0, stream>>>(fte_w1, fte_w2, w1t, w2t);

    // flow_up occupies out[0 .. 2*2*512*512), cost_global follows
    decoder_main<<<BN, 64, 0, stream>>>(cost_maps, cost_memory, coords1,
        w1t, fte_b1, w2t, fte_b2, ln1_g, ln1_b, ln2_g, ln2_b,
        wq, bq, wk, bk, wv, bv, wp, bp, fw1, fb1, fw2, fb2,
        out + 2*2*512*512);

    upsample_kernel<<<BN, 64, 0, stream>>>(coords1, up_mask, out);
}

// Round 2
// 355.112 us; speedup vs baseline: 1.1100x; 1.1100x over previous
//
#include <hip/hip_runtime.h>
#include <math.h>

#define BN   8192
#define DIMD 64
#define CLD  128
#define KTOK 8

// per-pixel LDS layout (floats)
#define CM_STRIDE 129           // 8 x 129 = 1032  (pad: kills 8-way conflicts on cm reads)
#define OFF_CM    0
#define OFF_TU    1032          // 64 x 8 = 512 (t/u scratch, one 64-c half at a time)
#define OFF_CORR  1544          // 88
#define OFF_VEC   1632          // 128
#define PIX_LDS   1792          // padded per-pixel footprint
#define PPB       4             // pixels (waves) per block

__device__ __forceinline__ float gelu_exact(float x){
    return 0.5f * x * (1.0f + erff(x * 0.70710678118654752f));
}

__device__ __forceinline__ float wave_sum64(float v){
    #pragma unroll
    for(int off = 32; off >= 1; off >>= 1) v += __shfl_xor(v, off, 64);
    return v;
}

// K0: transpose fte_w1 [64,81] -> [81,64] and fte_w2 [64,64] -> [64,64]
__global__ void prep_weights(const float* __restrict__ w1, const float* __restrict__ w2,
                             float* __restrict__ w1t, float* __restrict__ w2t){
    int idx = blockIdx.x * blockDim.x + threadIdx.x;
    if(idx < 64*81){ int o = idx / 81, c = idx % 81; w1t[c*64 + o] = w1[idx]; }
    if(idx < 64*64){ int o = idx / 64, c = idx % 64; w2t[c*64 + o] = w2[idx]; }
}

// Main fused kernel: 4 waves / block, one pixel per wave; lane t = feature dim.
__global__ __launch_bounds__(256) void decoder_main(
    const float* __restrict__ cost_maps, const float* __restrict__ cost_memory,
    const float* __restrict__ coords1,
    const float* __restrict__ w1t, const float* __restrict__ fte_b1,
    const float* __restrict__ w2t, const float* __restrict__ fte_b2,
    const float* __restrict__ ln1_g, const float* __restrict__ ln1_b,
    const float* __restrict__ ln2_g, const float* __restrict__ ln2_b,
    const float* __restrict__ wq, const float* __restrict__ bq,
    const float* __restrict__ wk, const float* __restrict__ bk,
    const float* __restrict__ wv, const float* __restrict__ bv,
    const float* __restrict__ wp, const float* __restrict__ bp,
    const float* __restrict__ fw1, const float* __restrict__ fb1,
    const float* __restrict__ fw2, const float* __restrict__ fb2,
    float* __restrict__ out_cg)
{
    __shared__ float smem[PPB * PIX_LDS];

    const int wv_id = threadIdx.x >> 6;
    const int t     = threadIdx.x & 63;
    const int pix   = blockIdx.x * PPB + wv_id;
    const int b = pix >> 12;
    const int h = (pix >> 6) & 63;
    const int w = pix & 63;

    float* S      = smem + wv_id * PIX_LDS;
    float* cm_s   = S + OFF_CM;
    float* tu_s   = S + OFF_TU;
    float* corr_s = S + OFF_CORR;
    float* vec_s  = S + OFF_VEC;

    const float cx = coords1[((b*2 + 0)*64 + h)*64 + w];
    const float cy = coords1[((b*2 + 1)*64 + h)*64 + w];

    // ---- stage cost_memory (1024 floats, coalesced; padded row stride 129)
    const float* cmp = cost_memory + (size_t)pix * (KTOK * CLD);
    #pragma unroll
    for(int i = 0; i < 16; i++){
        int l = i*64 + t;
        cm_s[(l >> 7) * CM_STRIDE + (l & 127)] = cmp[l];
    }

    // ---- correlation window: 81 bilinear samples from this pixel's 64x64 map
    const float* cmap = cost_maps + (size_t)pix * 4096;
    for(int e = t; e < 81; e += 64){
        int i = e / 9, j = e % 9;
        float sx = cx + (float)(i - 4);
        float sy = cy + (float)(j - 4);
        float x0 = floorf(sx), y0 = floorf(sy);
        float wx = sx - x0,   wy = sy - y0;
        float acc = 0.f;
        #pragma unroll
        for(int dy = 0; dy < 2; dy++){
            #pragma unroll
            for(int dx = 0; dx < 2; dx++){
                float xf = x0 + (float)dx, yf = y0 + (float)dy;
                bool valid = (xf >= 0.f) && (xf <= 63.f) && (yf >= 0.f) && (yf <= 63.f);
                int xi = min(max((int)xf, 0), 63);
                int yi = min(max((int)yf, 0), 63);
                float v = valid ? cmap[yi*64 + xi] : 0.f;
                float wgt = (dx ? wx : 1.f - wx) * (dy ? wy : 1.f - wy);
                acc += v * wgt;
            }
        }
        corr_s[e] = acc;
    }
    __syncthreads();

    // ---- FTE: 81->64, GELU, 64->64
    float q1 = fte_b1[t];
    #pragma unroll 4
    for(int c = 0; c < 81; c++) q1 += corr_s[c] * w1t[c*64 + t];
    q1 = gelu_exact(q1);
    vec_s[t] = q1;
    __syncthreads();

    float shortv = fte_b2[t];
    #pragma unroll 4
    for(int c = 0; c < 64; c++) shortv += vec_s[c] * w2t[c*64 + t];

    // ---- LN1 + sine position embedding
    float mean = wave_sum64(shortv) * (1.f/64.f);
    float d0   = shortv - mean;
    float var  = wave_sum64(d0*d0) * (1.f/64.f);
    float qn   = d0 * rsqrtf(var + 1e-5f) * ln1_g[t] + ln1_b[t];

    int   fi    = t & 15;
    float coord = (t < 32) ? cx : cy;
    float ang   = 3.14f * coord * (float)fi / 200.0f;
    float enc   = (t & 16) ? cosf(ang) : sinf(ang);

    __syncthreads();
    vec_s[t] = qn + enc;
    __syncthreads();

    float qlin = bq[t];
    #pragma unroll 4
    for(int c = 0; c < 64; c++) qlin += vec_s[c] * wq[c*64 + t];

    __syncthreads();
    vec_s[t] = qlin;       // q vector, lane = dim
    __syncthreads();

    // ---- K path: s[j,h] = sum_c cm[j,c] * t[c,h],  t[c,h] = sum_d q[h,d]*wk[c,h*8+d]
    //      (bk shifts all j equally per head -> cancels in softmax)
    const int h_  = t & 7;          // head (producer role)
    const int cl0 = t >> 3;         // c sub-lane
    float q8[8];
    #pragma unroll
    for(int d = 0; d < 8; d++) q8[d] = vec_s[h_*8 + d];

    float sacc = 0.f;
    const int j_ = t >> 3;          // token (consumer role)
    const int h2 = t & 7;           // head (consumer role)

    #pragma unroll
    for(int half = 0; half < 2; half++){
        const int c0 = half * 64;
        // produce t[c,h] for c in [c0, c0+64)
        #pragma unroll
        for(int i = 0; i < 8; i++){
            int cl = cl0 + 8*i;
            const float4* wk4 = (const float4*)(wk + (size_t)(c0 + cl)*64 + h_*8);
            float4 wa = wk4[0], wb = wk4[1];
            float tv = q8[0]*wa.x + q8[1]*wa.y + q8[2]*wa.z + q8[3]*wa.w
                     + q8[4]*wb.x + q8[5]*wb.y + q8[6]*wb.z + q8[7]*wb.w;
            tu_s[cl*8 + h_] = tv;
        }
        __syncthreads();
        // consume: s[j,h] partial
        #pragma unroll 4
        for(int cl = 0; cl < 64; cl++)
            sacc += cm_s[j_*CM_STRIDE + c0 + cl] * tu_s[cl*8 + h2];
        __syncthreads();
    }

    // ---- softmax over tokens j (lanes t = j*8+h, reduce over j: offsets 8,16,32)
    float sc = sacc * 0.35355339059327373f;
    float mx = sc;
    mx = fmaxf(mx, __shfl_xor(mx,  8, 64));
    mx = fmaxf(mx, __shfl_xor(mx, 16, 64));
    mx = fmaxf(mx, __shfl_xor(mx, 32, 64));
    float ex = expf(sc - mx);
    float se = ex;
    se += __shfl_xor(se,  8, 64);
    se += __shfl_xor(se, 16, 64);
    se += __shfl_xor(se, 32, 64);
    float a = ex / se;

    __syncthreads();
    vec_s[t] = a;          // a_s[j*8+h]
    __syncthreads();

    // ---- V path: out[h,d] = sum_c u_h[c]*wv[c,h*8+d] + bv,  u_h[c] = sum_j a[j,h]*cm[j,c]
    float aj[8];
    #pragma unroll
    for(int j = 0; j < 8; j++) aj[j] = vec_s[j*8 + h_];

    float attno = bv[t];
    const int h3 = t >> 3;          // head of this output dim

    #pragma unroll
    for(int half = 0; half < 2; half++){
        const int c0 = half * 64;
        #pragma unroll
        for(int i = 0; i < 8; i++){
            int cl = cl0 + 8*i;
            float uv = 0.f;
            #pragma unroll
            for(int j = 0; j < 8; j++)
                uv += aj[j] * cm_s[j*CM_STRIDE + c0 + cl];
            tu_s[cl*8 + h_] = uv;
        }
        __syncthreads();
        #pragma unroll 4
        for(int cl = 0; cl < 64; cl++)
            attno += tu_s[cl*8 + h3] * wv[(size_t)(c0 + cl)*64 + t];
        __syncthreads();
    }

    // ---- wp on concat(out, short), residual
    vec_s[t]      = attno;
    vec_s[64 + t] = shortv;
    __syncthreads();
    float x = bp[t];
    #pragma unroll 4
    for(int c = 0; c < 128; c++) x += vec_s[c] * wp[c*64 + t];
    x += shortv;

    // ---- LN2 + FFN, residual
    float m2 = wave_sum64(x) * (1.f/64.f);
    float dd = x - m2;
    float v2 = wave_sum64(dd*dd) * (1.f/64.f);
    float xn = dd * rsqrtf(v2 + 1e-5f) * ln2_g[t] + ln2_b[t];
    __syncthreads();
    vec_s[t] = xn;
    __syncthreads();
    float h1v = fb1[t];
    #pragma unroll 4
    for(int c = 0; c < 64; c++) h1v += vec_s[c] * fw1[c*64 + t];
    h1v = gelu_exact(h1v);
    __syncthreads();
    vec_s[t] = h1v;
    __syncthreads();
    float f2 = fb2[t];
    #pragma unroll 4
    for(int c = 0; c < 64; c++) f2 += vec_s[c] * fw2[c*64 + t];
    x += f2;

    out_cg[(((size_t)(b*64 + t))*64 + h)*64 + w] = x;
}

// Convex upsampling v2: block = (b, h, r), 512 threads.
// Coalesced LDS staging of the 72 mask channels this block needs; swizzled
// stride-68 tile so compute reads are <=2-way bank conflicts (free).
__global__ __launch_bounds__(512) void upsample_kernel(
    const float* __restrict__ coords1, const float* __restrict__ up_mask,
    float* __restrict__ out)
{
    __shared__ float mtile[9 * 544];      // [k][s*68 + w]
    __shared__ float fxs[3 * 64];
    __shared__ float fys[3 * 64];

    const int r = blockIdx.x & 7;
    const int h = (blockIdx.x >> 3) & 63;
    const int b = blockIdx.x >> 9;
    const int id = threadIdx.x;

    // stage masks: channel c = k*64 + r*8 + s, coalesced in w
    {
        const int s_ = id >> 6, w_ = id & 63;
        #pragma unroll
        for(int k = 0; k < 9; k++){
            int c = k*64 + r*8 + s_;
            mtile[k*544 + s_*68 + w_] =
                up_mask[(((size_t)b*576 + c)*64 + h)*64 + w_];
        }
    }
    // stage flow rows h-1, h, h+1 (zero-padded)
    if(id < 192){
        const int i = id >> 6, w_ = id & 63;
        const int hh = h + i - 1;
        float fx = 0.f, fy = 0.f;
        if(hh >= 0 && hh < 64){
            fx = 8.f * (coords1[((b*2 + 0)*64 + hh)*64 + w_] - (float)w_);
            fy = 8.f * (coords1[((b*2 + 1)*64 + hh)*64 + w_] - (float)hh);
        }
        fxs[i*64 + w_] = fx;
        fys[i*64 + w_] = fy;
    }
    __syncthreads();

    // compute: thread id = w*8 + s  (writes coalesced)
    const int w = id >> 3, s = id & 7;
    float m[9];
    #pragma unroll
    for(int k = 0; k < 9; k++) m[k] = mtile[k*544 + s*68 + w];
    float mx = m[0];
    #pragma unroll
    for(int k = 1; k < 9; k++) mx = fmaxf(mx, m[k]);
    float se = 0.f;
    #pragma unroll
    for(int k = 0; k < 9; k++){ m[k] = expf(m[k] - mx); se += m[k]; }
    float inv = 1.f / se;

    float ox = 0.f, oy = 0.f;
    #pragma unroll
    for(int k = 0; k < 9; k++){
        int i = k / 3, j = k % 3;
        int ww = w + j - 1;
        float fx = 0.f, fy = 0.f;
        if(ww >= 0 && ww < 64){
            fx = fxs[i*64 + ww];
            fy = fys[i*64 + ww];
        }
        ox += m[k] * fx;
        oy += m[k] * fy;
    }
    ox *= inv; oy *= inv;

    const size_t row = (size_t)(h*8 + r) * 512 + w*8 + s;
    out[(size_t)(b*2 + 0)*262144 + row] = ox;
    out[(size_t)(b*2 + 1)*262144 + row] = oy;
}

extern "C" void kernel_launch(void* const* d_in, const int* in_sizes, int n_in,
                              void* d_out, int out_size, void* d_ws, size_t ws_size,
                              hipStream_t stream)
{
    const float* cost_maps   = (const float*)d_in[0];
    const float* cost_memory = (const float*)d_in[1];
    const float* coords1     = (const float*)d_in[2];
    const float* up_mask     = (const float*)d_in[3];
    const float* fte_w1      = (const float*)d_in[4];
    const float* fte_b1      = (const float*)d_in[5];
    const float* fte_w2      = (const float*)d_in[6];
    const float* fte_b2      = (const float*)d_in[7];
    const float* ln1_g       = (const float*)d_in[8];
    const float* ln1_b       = (const float*)d_in[9];
    const float* ln2_g       = (const float*)d_in[10];
    const float* ln2_b       = (const float*)d_in[11];
    const float* wq          = (const float*)d_in[12];
    const float* bq          = (const float*)d_in[13];
    const float* wk          = (const float*)d_in[14];
    const float* bk          = (const float*)d_in[15];
    const float* wv          = (const float*)d_in[16];
    const float* bv          = (const float*)d_in[17];
    const float* wp          = (const float*)d_in[18];
    const float* bp          = (const float*)d_in[19];
    const float* fw1         = (const float*)d_in[20];
    const float* fb1         = (const float*)d_in[21];
    const float* fw2         = (const float*)d_in[22];
    const float* fb2         = (const float*)d_in[23];
    float* out = (float*)d_out;

    float* w1t = (float*)d_ws;          // 81*64 floats
    float* w2t = w1t + 81*64;           // 64*64 floats

    prep_weights<<<40, 256, 0, stream>>>(fte_w1, fte_w2, w1t, w2t);

    decoder_main<<<BN/PPB, 64*PPB, 0, stream>>>(cost_maps, cost_memory, coords1,
        w1t, fte_b1, w2t, fte_b2, ln1_g, ln1_b, ln2_g, ln2_b,
        wq, bq, wk, bk, wv, bv, wp, bp, fw1, fb1, fw2, fb2,
        out + 2*2*512*512);

    upsample_kernel<<<2*64*8, 512, 0, stream>>>(coords1, up_mask, out);
}

// Round 4
// 271.314 us; speedup vs baseline: 1.4528x; 1.3089x over previous
//
#include <hip/hip_runtime.h>
#include <math.h>

typedef _Float16 h2 __attribute__((ext_vector_type(2)));

#if __has_builtin(__builtin_amdgcn_fdot2)
#define FDOT2(a,b,c) __builtin_amdgcn_fdot2((a),(b),(c),false)
#else
__device__ __forceinline__ float FDOT2(h2 a, h2 b, float c){
    return c + (float)a.x*(float)b.x + (float)a.y*(float)b.y;
}
#endif

__device__ __forceinline__ h2 pk2(float x, float y){
#if __has_builtin(__builtin_amdgcn_cvt_pkrtz)
    return __builtin_bit_cast(h2, __builtin_amdgcn_cvt_pkrtz(x, y));
#else
    h2 r; r.x = (_Float16)x; r.y = (_Float16)y; return r;
#endif
}
__device__ __forceinline__ unsigned h2u(h2 v){ return __builtin_bit_cast(unsigned, v); }
__device__ __forceinline__ h2 uh2(unsigned v){ return __builtin_bit_cast(h2, v); }

__device__ __forceinline__ float dot8(uint4 w, uint4 v, float acc){
    acc = FDOT2(uh2(w.x), uh2(v.x), acc);
    acc = FDOT2(uh2(w.y), uh2(v.y), acc);
    acc = FDOT2(uh2(w.z), uh2(v.z), acc);
    acc = FDOT2(uh2(w.w), uh2(v.w), acc);
    return acc;
}

__device__ __forceinline__ float gelu_exact(float x){
    return 0.5f * x * (1.0f + erff(x * 0.70710678118654752f));
}
__device__ __forceinline__ float wave_sum64(float v){
    #pragma unroll
    for(int off = 32; off >= 1; off >>= 1) v += __shfl_xor(v, off, 64);
    return v;
}
// same-wave LDS RAW fence: DS ops are in-order per wave; this drains lgkm and
// stops the compiler reordering LDS accesses across it. No __syncthreads needed.
__device__ __forceinline__ void lds_fence(){ __asm__ volatile("s_waitcnt lgkmcnt(0)" ::: "memory"); }

// ---------------- packed-weight layout in d_ws (dword offsets) ----------------
// All "consume" matrices: [t(64)][cp(padded)] rows, f16-pair per dword, pair over
// input channel c. Row strides chosen ≡ 4 (mod 8) so per-lane ds_read_b128 covers
// all 8 bank-quads per cycle (conflict-free).
#define W1T_OFF 0        // [64][44]  fte_w1^T pairs (81 c's, zero-padded)
#define W2T_OFF 2816     // [64][36]  fte_w2 (src [o][c])
#define WQ_OFF  5120     // [64][36]
#define FW1_OFF 7424     // [64][36]
#define FW2_OFF 9728     // [64][36]
#define WV_OFF  12032    // [64][68]
#define WP_OFF  16384    // [64][68]
#define WK_OFF  20736    // [128 c][36]: dword hp = h*4+dp holds pair (wk[c][2hp], wk[c][2hp+1])
#define WTOT    25344    // dwords = 101.4 KB

// per-pixel LDS scratch (dword offsets within a wave's region)
#define CMO   0          // cm_h  [8 j][68]: pairs over c
#define TUO   544        // tu_h / u_h [8 h][68]: pairs over c
#define CORRO 1088       // corr pairs [44]
#define QPO   1132       // generic 64-vec pair buffer [36] (q1 / qn+enc / xn / h1)
#define CCO   1168       // concat pairs [64]
#define ASO   1232       // attention weights a, f32 [64]
#define PIXDW 1296
#define LDSDW (WTOT + 8*PIXDW)   // 35712 dw = 142,848 B (<= 160 KB/workgroup, CDNA4)

// K0: pack all weight matrices to f16-pair layouts in d_ws.
__global__ void prep_weights(const float* __restrict__ w1, const float* __restrict__ w2,
                             const float* __restrict__ wq, const float* __restrict__ fw1,
                             const float* __restrict__ fw2, const float* __restrict__ wv,
                             const float* __restrict__ wp, const float* __restrict__ wk,
                             unsigned* __restrict__ ws){
    int idx = blockIdx.x * blockDim.x + threadIdx.x;
    if(idx >= WTOT) return;
    float a = 0.f, b = 0.f;
    if(idx < W2T_OFF){                       // W1T [64][44], src w1 [o=64][c=81]
        int t = idx / 44, cp = idx % 44;
        if(2*cp   < 81) a = w1[t*81 + 2*cp];
        if(2*cp+1 < 81) b = w1[t*81 + 2*cp+1];
    } else if(idx < WQ_OFF){                 // W2T [64][36], src w2 [o=64][c=64]
        int r = idx - W2T_OFF; int t = r / 36, cp = r % 36;
        if(cp < 32){ a = w2[t*64 + 2*cp]; b = w2[t*64 + 2*cp+1]; }
    } else if(idx < FW1_OFF){                // WQ [64][36], src wq [c=64][o=64]
        int r = idx - WQ_OFF; int t = r / 36, cp = r % 36;
        if(cp < 32){ a = wq[(2*cp)*64 + t]; b = wq[(2*cp+1)*64 + t]; }
    } else if(idx < FW2_OFF){                // FW1
        int r = idx - FW1_OFF; int t = r / 36, cp = r % 36;
        if(cp < 32){ a = fw1[(2*cp)*64 + t]; b = fw1[(2*cp+1)*64 + t]; }
    } else if(idx < WV_OFF){                 // FW2
        int r = idx - FW2_OFF; int t = r / 36, cp = r % 36;
        if(cp < 32){ a = fw2[(2*cp)*64 + t]; b = fw2[(2*cp+1)*64 + t]; }
    } else if(idx < WP_OFF){                 // WV [64][68], src wv [c=128][o=64]
        int r = idx - WV_OFF; int t = r / 68, cp = r % 68;
        if(cp < 64){ a = wv[(2*cp)*64 + t]; b = wv[(2*cp+1)*64 + t]; }
    } else if(idx < WK_OFF){                 // WP [64][68], src wp [c=128][o=64]
        int r = idx - WP_OFF; int t = r / 68, cp = r % 68;
        if(cp < 64){ a = wp[(2*cp)*64 + t]; b = wp[(2*cp+1)*64 + t]; }
    } else {                                 // WK [128][36], src wk [c=128][o=64]
        int r = idx - WK_OFF; int c = r / 36, hp = r % 36;
        if(hp < 32){ a = wk[c*64 + 2*hp]; b = wk[c*64 + 2*hp+1]; }
    }
    ws[idx] = h2u(pk2(a, b));
}

__device__ __forceinline__ float bilin(const float* __restrict__ cmap, float cx, float cy, int e){
    int i = e / 9, j = e - 9*i;
    float sx = cx + (float)(i - 4);
    float sy = cy + (float)(j - 4);
    float x0 = floorf(sx), y0 = floorf(sy);
    float wx = sx - x0,   wy = sy - y0;
    float acc = 0.f;
    #pragma unroll
    for(int dy = 0; dy < 2; dy++){
        #pragma unroll
        for(int dx = 0; dx < 2; dx++){
            float xf = x0 + (float)dx, yf = y0 + (float)dy;
            bool valid = (xf >= 0.f) && (xf <= 63.f) && (yf >= 0.f) && (yf <= 63.f);
            int xi = min(max((int)xf, 0), 63);
            int yi = min(max((int)yf, 0), 63);
            float v = valid ? cmap[yi*64 + xi] : 0.f;
            acc += v * ((dx ? wx : 1.f - wx) * (dy ? wy : 1.f - wy));
        }
    }
    return acc;
}

// Main kernel: grid=256 blocks x 512 threads. Weights live in LDS (shared by all
// 8 waves); each wave owns one pixel at a time, 4 sequential pixel-groups.
__global__ __launch_bounds__(512, 1) void decoder_main(
    const float* __restrict__ cost_maps, const float* __restrict__ cost_memory,
    const float* __restrict__ coords1, const unsigned* __restrict__ ws,
    const float* __restrict__ fte_b1, const float* __restrict__ fte_b2,
    const float* __restrict__ ln1_g, const float* __restrict__ ln1_b,
    const float* __restrict__ ln2_g, const float* __restrict__ ln2_b,
    const float* __restrict__ bq, const float* __restrict__ bv,
    const float* __restrict__ bp, const float* __restrict__ fb1,
    const float* __restrict__ fb2, float* __restrict__ out_cg)
{
    __shared__ unsigned sm[LDSDW];

    const int tid = threadIdx.x;
    const int wv  = tid >> 6;
    const int ln  = tid & 63;

    // ---- cooperative weight copy d_ws -> LDS (uint4, coalesced)
    {
        const uint4* src = (const uint4*)ws;
        uint4* dst = (uint4*)sm;
        for(int i = tid; i < WTOT/4; i += 512) dst[i] = src[i];
    }
    // per-lane biases/ln params (lane = feature dim)
    const float b1v = fte_b1[ln], b2v = fte_b2[ln];
    const float g1v = ln1_g[ln], be1 = ln1_b[ln];
    const float g2v = ln2_g[ln], be2 = ln2_b[ln];
    const float bqv = bq[ln], bvv = bv[ln], bpv = bp[ln];
    const float f1v = fb1[ln], f2v = fb2[ln];
    __syncthreads();   // the ONLY block-wide barrier

    unsigned* P = sm + WTOT + wv * PIXDW;
    float*    Pf = (float*)P;

    const int h_ = ln & 7;     // head (producer role)
    const int c0 = ln >> 3;    // c sub-lane (producer role)
    const int j_ = ln >> 3;    // token (K-consumer role)
    const int h3 = ln >> 3;    // head of this output dim

    int pix = blockIdx.x * 32 + wv;
    // prefetch group 0
    const float4* cm4p = (const float4*)cost_memory;
    float4 cmv0 = cm4p[(size_t)pix*256 +   0 + ln];
    float4 cmv1 = cm4p[(size_t)pix*256 +  64 + ln];
    float4 cmv2 = cm4p[(size_t)pix*256 + 128 + ln];
    float4 cmv3 = cm4p[(size_t)pix*256 + 192 + ln];
    float cx = coords1[(pix >> 12)*8192 + (pix & 4095)];
    float cy = coords1[(pix >> 12)*8192 + 4096 + (pix & 4095)];

    #pragma unroll 1
    for(int g = 0; g < 4; g++){
        // ---- stage cm pairs into LDS: value l0 = 4*(i4*64+ln)
        {
            float4 v; int l0, jt, cp0;
            #define STAGE(V, I4) \
                v = V; l0 = 4*((I4)*64 + ln); jt = l0 >> 7; cp0 = (l0 & 127) >> 1; \
                P[CMO + jt*68 + cp0]     = h2u(pk2(v.x, v.y)); \
                P[CMO + jt*68 + cp0 + 1] = h2u(pk2(v.z, v.w));
            STAGE(cmv0, 0) STAGE(cmv1, 1) STAGE(cmv2, 2) STAGE(cmv3, 3)
            #undef STAGE
        }
        // ---- bilinear correlation window -> corr pairs
        {
            const float* cmap = cost_maps + (size_t)pix * 4096;
            float cv = bilin(cmap, cx, cy, ln);
            float pr = __shfl_xor(cv, 1, 64);
            if((ln & 1) == 0) P[CORRO + (ln >> 1)] = h2u(pk2(cv, pr));
            float c2 = 0.f;
            if(ln < 17) c2 = bilin(cmap, cx, cy, 64 + ln);
            float pr2 = __shfl_xor(c2, 1, 64);
            if(ln < 17 && (ln & 1) == 0){
                float bb = (ln == 16) ? 0.f : pr2;
                P[CORRO + 32 + (ln >> 1)] = h2u(pk2(c2, bb));
            }
            if(ln < 3) P[CORRO + 41 + ln] = 0u;   // zero pads cp 41..43
        }
        // ---- prefetch next group
        int npix = pix + 8;
        float4 n0, n1, n2, n3; float ncx = 0.f, ncy = 0.f;
        if(g < 3){
            n0 = cm4p[(size_t)npix*256 +   0 + ln];
            n1 = cm4p[(size_t)npix*256 +  64 + ln];
            n2 = cm4p[(size_t)npix*256 + 128 + ln];
            n3 = cm4p[(size_t)npix*256 + 192 + ln];
            ncx = coords1[(npix >> 12)*8192 + (npix & 4095)];
            ncy = coords1[(npix >> 12)*8192 + 4096 + (npix & 4095)];
        }
        lds_fence();

        // ---- FTE1: 81->64 + GELU
        float q1 = b1v;
        {
            const uint4* wr = (const uint4*)&sm[W1T_OFF + ln*44];
            const uint4* ar = (const uint4*)&P[CORRO];
            #pragma unroll
            for(int gg = 0; gg < 11; gg++) q1 = dot8(wr[gg], ar[gg], q1);
        }
        q1 = gelu_exact(q1);
        {   // pack q1 -> QP
            float pr = __shfl_xor(q1, 1, 64);
            if((ln & 1) == 0) P[QPO + (ln >> 1)] = h2u(pk2(q1, pr));
        }
        lds_fence();
        // ---- FTE2: 64->64
        float shortv = b2v;
        {
            const uint4* wr = (const uint4*)&sm[W2T_OFF + ln*36];
            const uint4* ar = (const uint4*)&P[QPO];
            #pragma unroll
            for(int gg = 0; gg < 8; gg++) shortv = dot8(wr[gg], ar[gg], shortv);
        }
        // ---- LN1 + position encoding
        float mean = wave_sum64(shortv) * (1.f/64.f);
        float d0   = shortv - mean;
        float var  = wave_sum64(d0*d0) * (1.f/64.f);
        float qn   = d0 * rsqrtf(var + 1e-5f) * g1v + be1;
        {
            int   fi    = ln & 15;
            float coord = (ln < 32) ? cx : cy;
            float ang   = 3.14f * coord * (float)fi / 200.0f;
            float enc   = (ln & 16) ? cosf(ang) : sinf(ang);
            float qv    = qn + enc;
            float pr = __shfl_xor(qv, 1, 64);
            if((ln & 1) == 0) P[QPO + (ln >> 1)] = h2u(pk2(qv, pr));
        }
        lds_fence();
        // ---- Wq
        float qlin = bqv;
        {
            const uint4* wr = (const uint4*)&sm[WQ_OFF + ln*36];
            const uint4* ar = (const uint4*)&P[QPO];
            #pragma unroll
            for(int gg = 0; gg < 8; gg++) qlin = dot8(wr[gg], ar[gg], qlin);
        }
        // ---- K path: t[c,h] = sum_d q[h,d] wk[c,h*8+d]  (bk cancels in softmax)
        {
            uint4 qh4 = *(const uint4*)&P[QPO + h_*4];
            #pragma unroll
            for(int i = 0; i < 16; i++){
                int c = c0 + 8*i;
                uint4 wk4 = *(const uint4*)&sm[WK_OFF + c*36 + h_*4];
                float tv = dot8(wk4, qh4, 0.f);
                float prt = __shfl_xor(tv, 8, 64);
                if((c0 & 1) == 0) P[TUO + h_*68 + (c0 >> 1) + 4*i] = h2u(pk2(tv, prt));
            }
        }
        lds_fence();
        // s[j,h] = sum_cp dot2(cm[j], t[h])
        float sacc = 0.f;
        {
            const int hk = ln & 7;
            const uint4* cmr = (const uint4*)&P[CMO + j_*68];
            const uint4* tur = (const uint4*)&P[TUO + hk*68];
            #pragma unroll
            for(int gg = 0; gg < 16; gg++) sacc = dot8(cmr[gg], tur[gg], sacc);
        }
        // softmax over tokens (lanes ln = j*8+h; reduce over j)
        float sc = sacc * 0.35355339059327373f;
        float mx = sc;
        mx = fmaxf(mx, __shfl_xor(mx,  8, 64));
        mx = fmaxf(mx, __shfl_xor(mx, 16, 64));
        mx = fmaxf(mx, __shfl_xor(mx, 32, 64));
        float ex = expf(sc - mx);
        float se = ex;
        se += __shfl_xor(se,  8, 64);
        se += __shfl_xor(se, 16, 64);
        se += __shfl_xor(se, 32, 64);
        Pf[ASO + ln] = ex / se;
        lds_fence();
        // ---- V path: u[h][c] = sum_j a[j,h] cm[j,c]  (half2 pairs over c)
        {
            h2 aj2[8];
            #pragma unroll
            for(int j = 0; j < 8; j++){
                float av = Pf[ASO + j*8 + h_];
                aj2[j] = pk2(av, av);
            }
            #pragma unroll
            for(int i = 0; i < 8; i++){
                int cp = c0 + 8*i;
                h2 u2 = pk2(0.f, 0.f);
                #pragma unroll
                for(int j = 0; j < 8; j++)
                    u2 += aj2[j] * uh2(P[CMO + j*68 + cp]);
                P[TUO + h_*68 + cp] = h2u(u2);
            }
        }
        lds_fence();
        // attno = bv + sum_c u[h3][c] wv[c][ln]
        float attno = bvv;
        {
            const uint4* ur = (const uint4*)&P[TUO + h3*68];
            const uint4* wr = (const uint4*)&sm[WV_OFF + ln*68];
            #pragma unroll
            for(int gg = 0; gg < 16; gg++) attno = dot8(ur[gg], wr[gg], attno);
        }
        // ---- wp on concat(attno, short) + residual
        {
            float pa = __shfl_xor(attno, 1, 64);
            if((ln & 1) == 0) P[CCO + (ln >> 1)] = h2u(pk2(attno, pa));
            float psv = __shfl_xor(shortv, 1, 64);
            if((ln & 1) == 0) P[CCO + 32 + (ln >> 1)] = h2u(pk2(shortv, psv));
        }
        lds_fence();
        float x = bpv;
        {
            const uint4* wr = (const uint4*)&sm[WP_OFF + ln*68];
            const uint4* ar = (const uint4*)&P[CCO];
            #pragma unroll
            for(int gg = 0; gg < 16; gg++) x = dot8(wr[gg], ar[gg], x);
        }
        x += shortv;
        // ---- LN2 + FFN + residual
        float m2 = wave_sum64(x) * (1.f/64.f);
        float dd = x - m2;
        float v2 = wave_sum64(dd*dd) * (1.f/64.f);
        float xn = dd * rsqrtf(v2 + 1e-5f) * g2v + be2;
        {
            float pr = __shfl_xor(xn, 1, 64);
            if((ln & 1) == 0) P[QPO + (ln >> 1)] = h2u(pk2(xn, pr));
        }
        lds_fence();
        float h1v = f1v;
        {
            const uint4* wr = (const uint4*)&sm[FW1_OFF + ln*36];
            const uint4* ar = (const uint4*)&P[QPO];
            #pragma unroll
            for(int gg = 0; gg < 8; gg++) h1v = dot8(wr[gg], ar[gg], h1v);
        }
        h1v = gelu_exact(h1v);
        {
            float pr = __shfl_xor(h1v, 1, 64);
            if((ln & 1) == 0) P[QPO + (ln >> 1)] = h2u(pk2(h1v, pr));
        }
        lds_fence();
        float f2 = f2v;
        {
            const uint4* wr = (const uint4*)&sm[FW2_OFF + ln*36];
            const uint4* ar = (const uint4*)&P[QPO];
            #pragma unroll
            for(int gg = 0; gg < 8; gg++) f2 = dot8(wr[gg], ar[gg], f2);
        }
        x += f2;
        // store: cost_global [B,64,64,64]
        {
            int bb = pix >> 12, hh = (pix >> 6) & 63, ww = pix & 63;
            out_cg[(((size_t)(bb*64 + ln))*64 + hh)*64 + ww] = x;
        }
        pix = npix; cx = ncx; cy = ncy;
        cmv0 = n0; cmv1 = n1; cmv2 = n2; cmv3 = n3;
    }
}

// Convex upsampling (unchanged from round 2): block = (b,h,r), 512 threads.
__global__ __launch_bounds__(512) void upsample_kernel(
    const float* __restrict__ coords1, const float* __restrict__ up_mask,
    float* __restrict__ out)
{
    __shared__ float mtile[9 * 544];
    __shared__ float fxs[3 * 64];
    __shared__ float fys[3 * 64];

    const int r = blockIdx.x & 7;
    const int h = (blockIdx.x >> 3) & 63;
    const int b = blockIdx.x >> 9;
    const int id = threadIdx.x;

    {
        const int s_ = id >> 6, w_ = id & 63;
        #pragma unroll
        for(int k = 0; k < 9; k++){
            int c = k*64 + r*8 + s_;
            mtile[k*544 + s_*68 + w_] =
                up_mask[(((size_t)b*576 + c)*64 + h)*64 + w_];
        }
    }
    if(id < 192){
        const int i = id >> 6, w_ = id & 63;
        const int hh = h + i - 1;
        float fx = 0.f, fy = 0.f;
        if(hh >= 0 && hh < 64){
            fx = 8.f * (coords1[((b*2 + 0)*64 + hh)*64 + w_] - (float)w_);
            fy = 8.f * (coords1[((b*2 + 1)*64 + hh)*64 + w_] - (float)hh);
        }
        fxs[i*64 + w_] = fx;
        fys[i*64 + w_] = fy;
    }
    __syncthreads();

    const int w = id >> 3, s = id & 7;
    float m[9];
    #pragma unroll
    for(int k = 0; k < 9; k++) m[k] = mtile[k*544 + s*68 + w];
    float mx = m[0];
    #pragma unroll
    for(int k = 1; k < 9; k++) mx = fmaxf(mx, m[k]);
    float se = 0.f;
    #pragma unroll
    for(int k = 0; k < 9; k++){ m[k] = expf(m[k] - mx); se += m[k]; }
    float inv = 1.f / se;

    float ox = 0.f, oy = 0.f;
    #pragma unroll
    for(int k = 0; k < 9; k++){
        int i = k / 3, j = k % 3;
        int ww = w + j - 1;
        float fx = 0.f, fy = 0.f;
        if(ww >= 0 && ww < 64){
            fx = fxs[i*64 + ww];
            fy = fys[i*64 + ww];
        }
        ox += m[k] * fx;
        oy += m[k] * fy;
    }
    ox *= inv; oy *= inv;

    const size_t row = (size_t)(h*8 + r) * 512 + w*8 + s;
    out[(size_t)(b*2 + 0)*262144 + row] = ox;
    out[(size_t)(b*2 + 1)*262144 + row] = oy;
}

extern "C" void kernel_launch(void* const* d_in, const int* in_sizes, int n_in,
                              void* d_out, int out_size, void* d_ws, size_t ws_size,
                              hipStream_t stream)
{
    const float* cost_maps   = (const float*)d_in[0];
    const float* cost_memory = (const float*)d_in[1];
    const float* coords1     = (const float*)d_in[2];
    const float* up_mask     = (const float*)d_in[3];
    const float* fte_w1      = (const float*)d_in[4];
    const float* fte_b1      = (const float*)d_in[5];
    const float* fte_w2      = (const float*)d_in[6];
    const float* fte_b2      = (const float*)d_in[7];
    const float* ln1_g       = (const float*)d_in[8];
    const float* ln1_b       = (const float*)d_in[9];
    const float* ln2_g       = (const float*)d_in[10];
    const float* ln2_b       = (const float*)d_in[11];
    const float* wq          = (const float*)d_in[12];
    const float* bq          = (const float*)d_in[13];
    const float* wk          = (const float*)d_in[14];
    const float* bv          = (const float*)d_in[17];
    const float* wv          = (const float*)d_in[16];
    const float* wp          = (const float*)d_in[18];
    const float* bp          = (const float*)d_in[19];
    const float* fw1         = (const float*)d_in[20];
    const float* fb1         = (const float*)d_in[21];
    const float* fw2         = (const float*)d_in[22];
    const float* fb2         = (const float*)d_in[23];
    float* out = (float*)d_out;
    unsigned* wsu = (unsigned*)d_ws;

    prep_weights<<<(WTOT + 511)/512, 512, 0, stream>>>(
        fte_w1, fte_w2, wq, fw1, fw2, wv, wp, wk, wsu);

    decoder_main<<<256, 512, 0, stream>>>(cost_maps, cost_memory, coords1, wsu,
        fte_b1, fte_b2, ln1_g, ln1_b, ln2_g, ln2_b,
        bq, bv, bp, fb1, fb2,
        out + 2*2*512*512);

    upsample_kernel<<<2*64*8, 512, 0, stream>>>(coords1, up_mask, out);
}